// Round 9
// baseline (633.209 us; speedup 1.0000x reference)
//
#include <hip/hip_runtime.h>
#include <math.h>

#define HID 128
#define NG_GAUSS 50
#define TBL_P 8192
#define TBL_DMAX 12.8f
#define TBL_DT (TBL_DMAX / (float)TBL_P)
#define TBL_INV_DT ((float)TBL_P / TBL_DMAX)
#define PI_F 3.14159265358979323846f
#define NB 8           // source-row buckets (4096 rows = 1MB hw each)

typedef short bf16x8 __attribute__((ext_vector_type(8)));
typedef float f32x4 __attribute__((ext_vector_type(4)));

// fast shifted-softplus via HW transcendentals (v_exp_f32 / v_log_f32)
__device__ __forceinline__ float ssp_f(float x) {
  float e = __expf(-fabsf(x));
  return fmaxf(x, 0.f) + __logf(1.f + e) - 0.69314718055994530942f;
}
__device__ __forceinline__ unsigned short f2bf(float x) {
  unsigned u = __float_as_uint(x);
  unsigned r = (u + 0x7FFFu + ((u >> 16) & 1u)) >> 16;
  return (unsigned short)r;
}

// ---------------- edge precompute: pack (row<<13|i0), cull, bucket deg ----
__global__ __launch_bounds__(256) void k_edge_pre(
    const float* __restrict__ pos, const int* __restrict__ ei,
    int E, int* __restrict__ epack, int* __restrict__ deg)
{
  int e = blockIdx.x * 256 + threadIdx.x;
  if (e >= E) return;
  int r = ei[e];
  int c = ei[E + e];
  float dx = pos[3*r+0] - pos[3*c+0];
  float dy = pos[3*r+1] - pos[3*c+1];
  float dz = pos[3*r+2] - pos[3*c+2];
  float d = sqrtf(dx*dx + dy*dy + dz*dz);
  int i0 = (int)(d * TBL_INV_DT + 0.5f);
  if (i0 >= TBL_P) { epack[e] = -1; return; }  // d>=12.8: gaussians underflow,
                                               // zero biases => filter exactly 0
  epack[e] = (r << 13) | i0;
  atomicAdd(&deg[c * NB + (r >> 12)], 1);
}

// ---------------- exclusive scan over N*NB bucket degrees -----------------
__global__ __launch_bounds__(1024) void k_scan(
    const int* __restrict__ deg, int* __restrict__ ptr, int M)
{
  __shared__ int wsum[16];
  int t = threadIdx.x;
  int chunk = (M + 1023) / 1024;
  int b = t * chunk;
  int e2 = min(b + chunk, M);
  int s = 0;
  for (int i = b; i < e2; ++i) s += deg[i];
  int lane = t & 63, w = t >> 6;
  int ps = s;
  for (int o = 1; o < 64; o <<= 1) { int x = __shfl_up(ps, o); if (lane >= o) ps += x; }
  if (lane == 63) wsum[w] = ps;
  __syncthreads();
  if (w == 0 && lane < 16) {
    int v = wsum[lane];
    int pv = v;
    for (int o = 1; o < 16; o <<= 1) { int x = __shfl_up(pv, o); if (lane >= o) pv += x; }
    wsum[lane] = pv - v;  // exclusive
  }
  __syncthreads();
  int base = wsum[w] + ps - s;
  for (int i = b; i < e2; ++i) { ptr[i] = base; base += deg[i]; }
  if (t == 1023) ptr[M] = base;
}

// ---------------- scatter edges into bucket-sorted CSR order --------------
__global__ __launch_bounds__(256) void k_csr_scatter(
    const int* __restrict__ col, const int* __restrict__ epack,
    const int* __restrict__ ptr, int* __restrict__ cursor,
    int* __restrict__ csr, int E)
{
  int e = blockIdx.x * 256 + threadIdx.x;
  if (e >= E) return;
  int p = epack[e];
  if (p < 0) return;
  int c = col[e];
  int idx = c * NB + ((p >> 13) >> 12);
  int slot = ptr[idx] + atomicAdd(&cursor[idx], 1);
  csr[slot] = p;
}

// ---------------- weight prep: bf16, transposed [n][k], chunk-XOR swizzle -
// grid (L, 6 types, 2 k-halves)
__global__ __launch_bounds__(256) void k_wprep(
    const float* __restrict__ aw_w, const float* __restrict__ out_w1,
    const float* __restrict__ out_w2, const float* __restrict__ mlp_w2,
    const float* __restrict__ mlp_w1, const float* __restrict__ head_w1,
    unsigned short* __restrict__ awt, unsigned short* __restrict__ o1t,
    unsigned short* __restrict__ o2t, unsigned short* __restrict__ m2t,
    unsigned short* __restrict__ m1t, unsigned short* __restrict__ hwt)
{
  __shared__ float Wl[64][132];
  int l = blockIdx.x, t = blockIdx.y;
  int k0 = blockIdx.z * 64;
  const float* src; unsigned short* dst; int K; int NCOL = 128;
  switch (t) {
    case 0:  src = aw_w;   dst = awt; K = 128; break;
    case 1:  src = out_w1; dst = o1t; K = 128; break;
    case 2:  src = out_w2; dst = o2t; K = 128; break;
    case 3:  src = mlp_w2; dst = m2t; K = 128; break;
    case 4:  src = mlp_w1; dst = m1t; K = NG_GAUSS; break;
    default:
      if (l) return;
      src = head_w1; dst = hwt; K = 128; NCOL = 64; break;
  }
  src += (long)l * K * NCOL;
  dst += (long)l * 128 * 128;
  const int tid = threadIdx.x;
  for (int idx = tid; idx < 64 * 128; idx += 256) {
    int kk = idx >> 7, n = idx & 127;
    int k = k0 + kk;
    Wl[kk][n] = (k < K && n < NCOL) ? src[(long)k * NCOL + n] : 0.f;
  }
  __syncthreads();
  for (int idx = tid; idx < 128 * 8; idx += 256) {
    int n = idx >> 3, pl = idx & 7;
    int p = (k0 >> 3) + pl;            // stored chunk position
    int q = p ^ (n & 7);               // logical chunk (same 8-chunk half)
    int kk = (q << 3) - k0;
    ushort4 lo = make_ushort4(f2bf(Wl[kk+0][n]), f2bf(Wl[kk+1][n]),
                              f2bf(Wl[kk+2][n]), f2bf(Wl[kk+3][n]));
    ushort4 hi = make_ushort4(f2bf(Wl[kk+4][n]), f2bf(Wl[kk+5][n]),
                              f2bf(Wl[kk+6][n]), f2bf(Wl[kk+7][n]));
    *(ushort4*)(dst + ((long)n << 7) + (p << 3)) = lo;
    *(ushort4*)(dst + ((long)n << 7) + (p << 3) + 4) = hi;
  }
}

// ---------------- gaussian feature table bf16 [TBL_P][128] zero-padded ----
__global__ void k_ea_build(unsigned short* __restrict__ EA)
{
  int p = blockIdx.x;
  int g = threadIdx.x; // 128 threads
  float v = 0.f;
  if (g < NG_GAUSS) {
    float step = 10.0f / 49.0f;
    float off = g * step;
    float coeff = -0.5f / (step * step);
    float t = p * TBL_DT - off;
    v = __expf(coeff * t * t);
  }
  EA[p * 128 + g] = f2bf(v);
}

// ---------------- h init: h = emb[z] (fp32 + bf16 copy) -------------------
__global__ __launch_bounds__(256) void k_h_init(
    const float4* __restrict__ emb4, const int* __restrict__ z,
    float4* __restrict__ h4, ushort4* __restrict__ hb4, int N)
{
  int idx = blockIdx.x * 256 + threadIdx.x;
  if (idx >= N * 32) return;
  int n = idx >> 5, c = idx & 31;
  float4 v = emb4[z[n] * 32 + c];
  h4[idx] = v;
  hb4[idx] = make_ushort4(f2bf(v.x), f2bf(v.y), f2bf(v.z), f2bf(v.w));
}

// ---------------- fused GEMM chain (BM=32, single 32KB weight buffer) -----
__global__ __launch_bounds__(256) void k_fused(
    const unsigned short* __restrict__ X, long xstr,
    const unsigned short* __restrict__ Wa, long wastr,
    const float* __restrict__ ba, long bastr,
    const unsigned short* __restrict__ Wb, long wbstr,
    const float* __restrict__ bb, long bbstr,
    const float* __restrict__ R,
    void* __restrict__ out1, long o1str, int o1_bf16, int actB, int mulC,
    float dscale,
    const unsigned short* __restrict__ Wc, const float* __restrict__ bc,
    unsigned short* __restrict__ out2,
    const float* __restrict__ hw2, const float* __restrict__ hb2,
    const int* __restrict__ batchp, float* __restrict__ outp,
    int M)
{
  __shared__ unsigned short Xs[32][128];
  __shared__ unsigned short Wbuf[128][128];

  const int l = blockIdx.y;
  const int m0 = blockIdx.x * 32;
  const int tid = threadIdx.x;
  const unsigned short* Xb = X + (long)l * xstr;

  for (int idx = tid; idx < 512; idx += 256) {
    int r = idx >> 4, c = idx & 15;
    int m = m0 + r;
    int4 v = make_int4(0, 0, 0, 0);
    if (m < M) v = *(const int4*)(Xb + (long)m * 128 + c * 8);
    *(int4*)&Xs[r][(c ^ (r & 7)) << 3] = v;
  }
  {
    const unsigned short* W0 = Wa ? (Wa + (long)l * wastr) : (Wb + (long)l * wbstr);
    const int4* s = (const int4*)W0;
    int4* d = (int4*)Wbuf;
    for (int i = tid; i < 2048; i += 256) d[i] = s[i];
  }
  __syncthreads();

  const int wv = tid >> 6, lane = tid & 63;
  const int wr = wv >> 1, wc = wv & 1;
  const int lr = lane & 15, lk = lane >> 4;
  const int arow = (wr << 4) | lr;

  f32x4 acc[4];
  auto zacc = [&]() {
#pragma unroll
    for (int i = 0; i < 4; ++i)
#pragma unroll
      for (int j = 0; j < 4; ++j) acc[i][j] = 0.f;
  };
  auto gemm = [&]() {
#pragma unroll
    for (int kc = 0; kc < 4; ++kc) {
      int q = (kc << 2) | lk;
      bf16x8 a = *(const bf16x8*)&Xs[arow][(q ^ (arow & 7)) << 3];
#pragma unroll
      for (int nt = 0; nt < 4; ++nt) {
        int n = (wc << 6) | (nt << 4) | lr;
        bf16x8 b = *(const bf16x8*)(&Wbuf[0][0] + n * 128 + ((q ^ (n & 7)) << 3));
        acc[nt] = __builtin_amdgcn_mfma_f32_16x16x32_bf16(a, b, acc[nt], 0, 0, 0);
      }
    }
  };

  if (Wa) {
    const float* bab = ba + (long)l * bastr;
    zacc();
    gemm();
    __syncthreads();
#pragma unroll
    for (int nt = 0; nt < 4; ++nt) {
      int col = (wc << 6) | (nt << 4) | lr;
      float bv = bab[col];
#pragma unroll
      for (int r2 = 0; r2 < 4; ++r2) {
        int row = (wr << 4) | (lk << 2) | r2;
        float v2 = ssp_f(acc[nt][r2] + bv);
        int cch = col >> 3;
        Xs[row][((cch ^ (row & 7)) << 3) | (col & 7)] = f2bf(v2);
      }
    }
    {
      const int4* s = (const int4*)(Wb + (long)l * wbstr);
      int4* d = (int4*)Wbuf;
      for (int i = tid; i < 2048; i += 256) d[i] = s[i];
    }
    __syncthreads();
  }

  const float* bbb = bb + (long)l * bbstr;
  zacc();
  gemm();
  __syncthreads();

#pragma unroll
  for (int nt = 0; nt < 4; ++nt) {
    int col = (wc << 6) | (nt << 4) | lr;
    float bv = bbb[col];
#pragma unroll
    for (int r2 = 0; r2 < 4; ++r2) {
      int row = (wr << 4) | (lk << 2) | r2;
      int m = m0 + row;
      float v2 = acc[nt][r2] + bv;
      if (actB) v2 = ssp_f(v2);
      if (R && m < M) v2 += R[(long)m * 128 + col];
      if (mulC) {
        float d = (float)m * dscale;
        v2 *= 0.5f * (__cosf(d * (PI_F / 10.0f)) + 1.0f);
      }
      if (m < M && out1) {
        if (o1_bf16)
          ((unsigned short*)out1)[(long)l * o1str + (long)m * 128 + col] = f2bf(v2);
        else
          ((float*)out1)[(long)l * o1str + (long)m * 128 + col] = v2;
      }
      if (Wc) {
        int cch = col >> 3;
        Xs[row][((cch ^ (row & 7)) << 3) | (col & 7)] = f2bf(v2);
      }
    }
  }

  if (Wc) {
    {
      const int4* s = (const int4*)Wc;
      int4* d = (int4*)Wbuf;
      for (int i = tid; i < 2048; i += 256) d[i] = s[i];
    }
    __syncthreads();
    zacc();
    gemm();
    if (hw2) {
      if (wc == 0) {
        float b1v[4], w2v[4];
#pragma unroll
        for (int nt = 0; nt < 4; ++nt) {
          int col = (nt << 4) | lr;
          b1v[nt] = bc[col];
          w2v[nt] = hw2[col];
        }
        float bias2 = hb2[0];
#pragma unroll
        for (int r2 = 0; r2 < 4; ++r2) {
          float sv = 0.f;
#pragma unroll
          for (int nt = 0; nt < 4; ++nt)
            sv += ssp_f(acc[nt][r2] + b1v[nt]) * w2v[nt];
          sv += __shfl_xor(sv, 1);
          sv += __shfl_xor(sv, 2);
          sv += __shfl_xor(sv, 4);
          sv += __shfl_xor(sv, 8);
          if (lr == 0) {
            int m = m0 + (wr << 4) + (lk << 2) + r2;
            if (m < M) atomicAdd(&outp[batchp[m]], sv + bias2);
          }
        }
      }
    } else {
#pragma unroll
      for (int nt = 0; nt < 4; ++nt) {
        int col = (wc << 6) | (nt << 4) | lr;
        float bv = bc[col];
#pragma unroll
        for (int r2 = 0; r2 < 4; ++r2) {
          int row = (wr << 4) | (lk << 2) | r2;
          int m = m0 + row;
          if (m < M)
            out2[(long)m * 128 + col] = f2bf(acc[nt][r2] + bv);
        }
      }
    }
  }
}

// ---------------- conv: per-node gather, scalar csr, 8-wide pipelined -----
// Edges are bucket-sorted by source-row range (1MB hw slices) so the live
// gather working set (~1MB hw + 2MB T) fits each XCD's 4MB L2.
#define CONV_EDGE(PK, AX, AY) {                                              \
    unsigned pr = (unsigned)(PK);                                            \
    unsigned tv = *(const unsigned*)(T + ((size_t)(pr & 8191u) << 7) + la);  \
    unsigned hv = *(const unsigned*)(hw + ((size_t)(pr >> 13) << 7) + la);   \
    float w0 = __uint_as_float(tv << 16), w1 = __uint_as_float(tv & 0xffff0000u); \
    float h0 = __uint_as_float(hv << 16), h1 = __uint_as_float(hv & 0xffff0000u); \
    AX = fmaf(w0, h0, AX); AY = fmaf(w1, h1, AY); }

__global__ __launch_bounds__(256) void k_conv(
    const int* __restrict__ csr, const int* __restrict__ ptr,
    const unsigned short* __restrict__ T, const unsigned short* __restrict__ hw,
    unsigned short* __restrict__ convb, int N)
{
  int wid = __builtin_amdgcn_readfirstlane((blockIdx.x * 256 + threadIdx.x) >> 6);
  int lane = threadIdx.x & 63;
  if (wid >= N) return;
  int s = __builtin_amdgcn_readfirstlane(ptr[wid * NB]);
  int e = __builtin_amdgcn_readfirstlane(ptr[wid * NB + NB]);
  const int la = lane << 1;
  float ax[8], ay[8];
#pragma unroll
  for (int i = 0; i < 8; ++i) { ax[i] = 0.f; ay[i] = 0.f; }
  int j = s;
  if (j + 8 <= e) {
    int cc[8];
#pragma unroll
    for (int i = 0; i < 8; ++i) cc[i] = __builtin_amdgcn_readfirstlane(csr[j + i]);
    for (; j + 16 <= e; j += 8) {
      unsigned tv[8], hv[8];
#pragma unroll
      for (int i = 0; i < 8; ++i) {
        unsigned pr = (unsigned)cc[i];
        tv[i] = *(const unsigned*)(T + ((size_t)(pr & 8191u) << 7) + la);
        hv[i] = *(const unsigned*)(hw + ((size_t)(pr >> 13) << 7) + la);
      }
#pragma unroll
      for (int i = 0; i < 8; ++i) cc[i] = __builtin_amdgcn_readfirstlane(csr[j + 8 + i]);
#pragma unroll
      for (int i = 0; i < 8; ++i) {
        float w0 = __uint_as_float(tv[i] << 16), w1 = __uint_as_float(tv[i] & 0xffff0000u);
        float h0 = __uint_as_float(hv[i] << 16), h1 = __uint_as_float(hv[i] & 0xffff0000u);
        ax[i] = fmaf(w0, h0, ax[i]); ay[i] = fmaf(w1, h1, ay[i]);
      }
    }
    {
      unsigned tv[8], hv[8];
#pragma unroll
      for (int i = 0; i < 8; ++i) {
        unsigned pr = (unsigned)cc[i];
        tv[i] = *(const unsigned*)(T + ((size_t)(pr & 8191u) << 7) + la);
        hv[i] = *(const unsigned*)(hw + ((size_t)(pr >> 13) << 7) + la);
      }
#pragma unroll
      for (int i = 0; i < 8; ++i) {
        float w0 = __uint_as_float(tv[i] << 16), w1 = __uint_as_float(tv[i] & 0xffff0000u);
        float h0 = __uint_as_float(hv[i] << 16), h1 = __uint_as_float(hv[i] & 0xffff0000u);
        ax[i] = fmaf(w0, h0, ax[i]); ay[i] = fmaf(w1, h1, ay[i]);
      }
    }
    j += 8;
  }
  for (; j < e; ++j) {
    unsigned pr = (unsigned)__builtin_amdgcn_readfirstlane(csr[j]);
    unsigned tv = *(const unsigned*)(T + ((size_t)(pr & 8191u) << 7) + la);
    unsigned hv = *(const unsigned*)(hw + ((size_t)(pr >> 13) << 7) + la);
    float w0 = __uint_as_float(tv << 16), w1 = __uint_as_float(tv & 0xffff0000u);
    float h0 = __uint_as_float(hv << 16), h1 = __uint_as_float(hv & 0xffff0000u);
    ax[0] = fmaf(w0, h0, ax[0]); ay[0] = fmaf(w1, h1, ay[0]);
  }
  float axs = ((ax[0] + ax[1]) + (ax[2] + ax[3])) + ((ax[4] + ax[5]) + (ax[6] + ax[7]));
  float ays = ((ay[0] + ay[1]) + (ay[2] + ay[3])) + ((ay[4] + ay[5]) + (ay[6] + ay[7]));
  unsigned outw = (unsigned)f2bf(axs) | ((unsigned)f2bf(ays) << 16);
  *(unsigned*)(convb + ((size_t)wid << 7) + la) = outw;
}

extern "C" void kernel_launch(void* const* d_in, const int* in_sizes, int n_in,
                              void* d_out, int out_size, void* d_ws, size_t ws_size,
                              hipStream_t stream) {
  (void)n_in; (void)ws_size;
  const float* pos     = (const float*)d_in[0];
  const int*   z       = (const int*)d_in[1];
  const int*   batch   = (const int*)d_in[2];
  const int*   ei      = (const int*)d_in[3];
  const float* emb     = (const float*)d_in[4];
  const float* mlp_w1  = (const float*)d_in[5];
  const float* mlp_b1  = (const float*)d_in[6];
  const float* mlp_w2  = (const float*)d_in[7];
  const float* mlp_b2  = (const float*)d_in[8];
  const float* aw_w    = (const float*)d_in[9];
  const float* aw_b    = (const float*)d_in[10];
  const float* out_w1  = (const float*)d_in[11];
  const float* out_b1  = (const float*)d_in[12];
  const float* out_w2  = (const float*)d_in[13];
  const float* out_b2  = (const float*)d_in[14];
  const float* head_w1 = (const float*)d_in[15];
  const float* head_b1 = (const float*)d_in[16];
  const float* head_w2 = (const float*)d_in[17];
  const float* head_b2 = (const float*)d_in[18];

  const int N  = in_sizes[0] / 3;
  const int E  = in_sizes[3] / 2;
  const int NG = out_size;
  const int L  = in_sizes[5] / (NG_GAUSS * HID);

  char* ws = (char*)d_ws;
  size_t off = 0;
  auto alloc = [&](size_t bytes) -> void* {
    off = (off + 255) & ~(size_t)255;
    void* p = ws + off;
    off += bytes;
    return p;
  };

  const size_t nh = (size_t)N * HID;
  float* h_buf = (float*)alloc(nh * 4 > (size_t)E * 4 ? nh * 4 : (size_t)E * 4);
  int*   epack = (int*)h_buf;                   // alias (disjoint lifetime)
  unsigned short* hb    = (unsigned short*)alloc(nh * 2);
  unsigned short* hw    = (unsigned short*)alloc(nh * 2);
  unsigned short* convb = (unsigned short*)alloc(
      nh * 2 > (size_t)TBL_P * 128 * 2 ? nh * 2 : (size_t)TBL_P * 128 * 2);
  unsigned short* EA    = convb;                // alias (EA used pre-conv)
  int* csr = (int*)alloc((size_t)E * 4);
  unsigned short* T   = (unsigned short*)alloc((size_t)L * TBL_P * 128 * 2);
  unsigned short* awt = (unsigned short*)alloc((size_t)L * 16384 * 2);
  unsigned short* o1t = (unsigned short*)alloc((size_t)L * 16384 * 2);
  unsigned short* o2t = (unsigned short*)alloc((size_t)L * 16384 * 2);
  unsigned short* m2t = (unsigned short*)alloc((size_t)L * 16384 * 2);
  unsigned short* m1t = (unsigned short*)alloc((size_t)L * 16384 * 2);
  unsigned short* hwt = (unsigned short*)alloc((size_t)16384 * 2);
  int* deg    = (int*)alloc((size_t)N * NB * 4);
  int* ptr    = (int*)alloc(((size_t)N * NB + 1) * 4);
  int* cursor = (int*)alloc((size_t)N * NB * 4);

  hipMemsetAsync(deg, 0, (size_t)N * NB * 4, stream);
  hipMemsetAsync(cursor, 0, (size_t)N * NB * 4, stream);
  hipMemsetAsync(d_out, 0, (size_t)NG * 4, stream);

  int egrid = (E + 255) / 256;
  k_edge_pre<<<egrid, 256, 0, stream>>>(pos, ei, E, epack, deg);
  k_scan<<<1, 1024, 0, stream>>>(deg, ptr, N * NB);
  k_csr_scatter<<<egrid, 256, 0, stream>>>(ei + E, epack, ptr, cursor, csr, E);

  k_wprep<<<dim3(L, 6, 2), 256, 0, stream>>>(aw_w, out_w1, out_w2, mlp_w2,
                                             mlp_w1, head_w1,
                                             awt, o1t, o2t, m2t, m1t, hwt);
  k_ea_build<<<TBL_P, 128, 0, stream>>>(EA);

  // filter tables: T_l = ssp(ssp(EA@w1+b1)@w2+b2) * C(d), bf16, batched
  k_fused<<<dim3(TBL_P / 32, L), 256, 0, stream>>>(
      EA, 0L,
      m1t, 16384L, mlp_b1, 128L,
      m2t, 16384L, mlp_b2, 128L,
      (const float*)0,
      T, (long)TBL_P * 128, 1 /*bf16*/, 1 /*ssp*/, 1 /*mulC*/, TBL_DT,
      (const unsigned short*)0, (const float*)0, (unsigned short*)0,
      (const float*)0, (const float*)0, (const int*)0, (float*)0,
      TBL_P);

  k_h_init<<<(N * 32 + 255) / 256, 256, 0, stream>>>(
      (const float4*)emb, z, (float4*)h_buf, (ushort4*)hb, N);

  const int ngrid = (N + 31) / 32;
  const int wgrid = (N * 64 + 255) / 256;

  // initial hw = h0 @ aw_w[0] + aw_b[0]
  k_fused<<<dim3(ngrid, 1), 256, 0, stream>>>(
      hb, 0L,
      (const unsigned short*)0, 0L, (const float*)0, 0L,
      awt, 0L, aw_b, 0L,
      (const float*)0,
      hw, 0L, 1 /*bf16*/, 0, 0, 0.f,
      (const unsigned short*)0, (const float*)0, (unsigned short*)0,
      (const float*)0, (const float*)0, (const int*)0, (float*)0,
      N);

  for (int l = 0; l < L; ++l) {
    k_conv<<<wgrid, 256, 0, stream>>>(
        csr, ptr, T + (size_t)l * TBL_P * 128, hw, convb, N);
    const int last = (l + 1 == L);
    const unsigned short* Wc = last ? hwt : (awt + (size_t)(l + 1) * 16384);
    const float* bc = last ? head_b1 : (aw_b + (size_t)(l + 1) * 128);
    k_fused<<<dim3(ngrid, 1), 256, 0, stream>>>(
        convb, 0L,
        o1t + (size_t)l * 16384, 0L, out_b1 + (size_t)l * 128, 0L,
        o2t + (size_t)l * 16384, 0L, out_b2 + (size_t)l * 128, 0L,
        h_buf,
        last ? (void*)0 : (void*)h_buf, 0L, 0 /*fp32*/, 0 /*no act*/, 0, 0.f,
        Wc, bc, last ? (unsigned short*)0 : hw,
        last ? head_w2 : (const float*)0, last ? head_b2 : (const float*)0,
        last ? batch : (const int*)0, last ? (float*)d_out : (float*)0,
        N);
  }
}

// Round 10
// 389.539 us; speedup vs baseline: 1.6255x; 1.6255x over previous
//
#include <hip/hip_runtime.h>
#include <math.h>

#define HID 128
#define NG_GAUSS 50
#define TBL_P 8192
#define TBL_DMAX 12.8f
#define TBL_DT (TBL_DMAX / (float)TBL_P)
#define TBL_INV_DT ((float)TBL_P / TBL_DMAX)
#define PI_F 3.14159265358979323846f
#define NB 8           // source-row buckets (4096 rows = 1MB hw each)

typedef short bf16x8 __attribute__((ext_vector_type(8)));
typedef float f32x4 __attribute__((ext_vector_type(4)));

// fast shifted-softplus via HW transcendentals (v_exp_f32 / v_log_f32)
__device__ __forceinline__ float ssp_f(float x) {
  float e = __expf(-fabsf(x));
  return fmaxf(x, 0.f) + __logf(1.f + e) - 0.69314718055994530942f;
}
__device__ __forceinline__ unsigned short f2bf(float x) {
  unsigned u = __float_as_uint(x);
  unsigned r = (u + 0x7FFFu + ((u >> 16) & 1u)) >> 16;
  return (unsigned short)r;
}

// ---------------- edge precompute: pack (row<<13|i0), cull, bucket deg ----
__global__ __launch_bounds__(256) void k_edge_pre(
    const float* __restrict__ pos, const int* __restrict__ ei,
    int E, int* __restrict__ epack, int* __restrict__ deg)
{
  int e = blockIdx.x * 256 + threadIdx.x;
  if (e >= E) return;
  int r = ei[e];
  int c = ei[E + e];
  float dx = pos[3*r+0] - pos[3*c+0];
  float dy = pos[3*r+1] - pos[3*c+1];
  float dz = pos[3*r+2] - pos[3*c+2];
  float d = sqrtf(dx*dx + dy*dy + dz*dz);
  int i0 = (int)(d * TBL_INV_DT + 0.5f);
  if (i0 >= TBL_P) { epack[e] = -1; return; }  // d>=12.8: gaussians underflow,
                                               // zero biases => filter exactly 0
  epack[e] = (r << 13) | i0;
  atomicAdd(&deg[c * NB + (r >> 12)], 1);
}

// ---------------- multi-block exclusive scan (3 phases) -------------------
// phase 1: per-block (2048 elems) exclusive scan + block sum
__global__ __launch_bounds__(1024) void k_scan1(
    const int* __restrict__ deg, int* __restrict__ ptr,
    int* __restrict__ bsum, int M)
{
  __shared__ int wsum[16];
  int base = blockIdx.x * 2048;
  int t = threadIdx.x;
  int i0 = base + 2 * t;
  int v0 = (i0 < M) ? deg[i0] : 0;
  int v1 = (i0 + 1 < M) ? deg[i0 + 1] : 0;
  int s = v0 + v1;
  int lane = t & 63, w = t >> 6;
  int ps = s;
  for (int o = 1; o < 64; o <<= 1) { int x = __shfl_up(ps, o); if (lane >= o) ps += x; }
  if (lane == 63) wsum[w] = ps;
  __syncthreads();
  if (w == 0 && lane < 16) {
    int v = wsum[lane];
    int pv = v;
    for (int o = 1; o < 16; o <<= 1) { int x = __shfl_up(pv, o); if (lane >= o) pv += x; }
    wsum[lane] = pv - v;  // exclusive
  }
  __syncthreads();
  int ex = wsum[w] + ps - s;       // block-local exclusive prefix
  if (i0 < M) ptr[i0] = ex;
  if (i0 + 1 < M) ptr[i0 + 1] = ex + v0;
  if (t == 1023) bsum[blockIdx.x] = ex + s;  // block total
}

// phase 2: single-block exclusive scan of G block sums; bsum[G] = total
__global__ __launch_bounds__(1024) void k_scan2(int* __restrict__ bsum, int G)
{
  __shared__ int wsum[16];
  int t = threadIdx.x;
  int s = (t < G) ? bsum[t] : 0;
  int lane = t & 63, w = t >> 6;
  int ps = s;
  for (int o = 1; o < 64; o <<= 1) { int x = __shfl_up(ps, o); if (lane >= o) ps += x; }
  if (lane == 63) wsum[w] = ps;
  __syncthreads();
  if (w == 0 && lane < 16) {
    int v = wsum[lane];
    int pv = v;
    for (int o = 1; o < 16; o <<= 1) { int x = __shfl_up(pv, o); if (lane >= o) pv += x; }
    wsum[lane] = pv - v;
  }
  __syncthreads();
  int ex = wsum[w] + ps - s;
  if (t < G) bsum[t] = ex;
  if (t == G - 1) bsum[G] = ex + s;  // grand total
}

// phase 3: add block bases; write ptr[M] = total
__global__ __launch_bounds__(1024) void k_scan3(
    int* __restrict__ ptr, const int* __restrict__ bsum, int M, int G)
{
  int base = blockIdx.x * 2048;
  int t = threadIdx.x;
  int add = bsum[blockIdx.x];
  int i0 = base + 2 * t;
  if (i0 < M) ptr[i0] += add;
  if (i0 + 1 < M) ptr[i0 + 1] += add;
  if (blockIdx.x == 0 && t == 0) ptr[M] = bsum[G];
}

// ---------------- scatter edges into bucket-sorted CSR order --------------
__global__ __launch_bounds__(256) void k_csr_scatter(
    const int* __restrict__ col, const int* __restrict__ epack,
    const int* __restrict__ ptr, int* __restrict__ cursor,
    int* __restrict__ csr, int E)
{
  int e = blockIdx.x * 256 + threadIdx.x;
  if (e >= E) return;
  int p = epack[e];
  if (p < 0) return;
  int c = col[e];
  int idx = c * NB + ((p >> 13) >> 12);
  int slot = ptr[idx] + atomicAdd(&cursor[idx], 1);
  csr[slot] = p;
}

// ---------------- weight prep: bf16, transposed [n][k], chunk-XOR swizzle -
// grid (L, 6 types, 2 k-halves)
__global__ __launch_bounds__(256) void k_wprep(
    const float* __restrict__ aw_w, const float* __restrict__ out_w1,
    const float* __restrict__ out_w2, const float* __restrict__ mlp_w2,
    const float* __restrict__ mlp_w1, const float* __restrict__ head_w1,
    unsigned short* __restrict__ awt, unsigned short* __restrict__ o1t,
    unsigned short* __restrict__ o2t, unsigned short* __restrict__ m2t,
    unsigned short* __restrict__ m1t, unsigned short* __restrict__ hwt)
{
  __shared__ float Wl[64][132];
  int l = blockIdx.x, t = blockIdx.y;
  int k0 = blockIdx.z * 64;
  const float* src; unsigned short* dst; int K; int NCOL = 128;
  switch (t) {
    case 0:  src = aw_w;   dst = awt; K = 128; break;
    case 1:  src = out_w1; dst = o1t; K = 128; break;
    case 2:  src = out_w2; dst = o2t; K = 128; break;
    case 3:  src = mlp_w2; dst = m2t; K = 128; break;
    case 4:  src = mlp_w1; dst = m1t; K = NG_GAUSS; break;
    default:
      if (l) return;
      src = head_w1; dst = hwt; K = 128; NCOL = 64; break;
  }
  src += (long)l * K * NCOL;
  dst += (long)l * 128 * 128;
  const int tid = threadIdx.x;
  for (int idx = tid; idx < 64 * 128; idx += 256) {
    int kk = idx >> 7, n = idx & 127;
    int k = k0 + kk;
    Wl[kk][n] = (k < K && n < NCOL) ? src[(long)k * NCOL + n] : 0.f;
  }
  __syncthreads();
  for (int idx = tid; idx < 128 * 8; idx += 256) {
    int n = idx >> 3, pl = idx & 7;
    int p = (k0 >> 3) + pl;            // stored chunk position
    int q = p ^ (n & 7);               // logical chunk (same 8-chunk half)
    int kk = (q << 3) - k0;
    ushort4 lo = make_ushort4(f2bf(Wl[kk+0][n]), f2bf(Wl[kk+1][n]),
                              f2bf(Wl[kk+2][n]), f2bf(Wl[kk+3][n]));
    ushort4 hi = make_ushort4(f2bf(Wl[kk+4][n]), f2bf(Wl[kk+5][n]),
                              f2bf(Wl[kk+6][n]), f2bf(Wl[kk+7][n]));
    *(ushort4*)(dst + ((long)n << 7) + (p << 3)) = lo;
    *(ushort4*)(dst + ((long)n << 7) + (p << 3) + 4) = hi;
  }
}

// ---------------- gaussian feature table bf16 [TBL_P][128] zero-padded ----
__global__ void k_ea_build(unsigned short* __restrict__ EA)
{
  int p = blockIdx.x;
  int g = threadIdx.x; // 128 threads
  float v = 0.f;
  if (g < NG_GAUSS) {
    float step = 10.0f / 49.0f;
    float off = g * step;
    float coeff = -0.5f / (step * step);
    float t = p * TBL_DT - off;
    v = __expf(coeff * t * t);
  }
  EA[p * 128 + g] = f2bf(v);
}

// ---------------- h init: h = emb[z] (fp32 + bf16 copy) -------------------
__global__ __launch_bounds__(256) void k_h_init(
    const float4* __restrict__ emb4, const int* __restrict__ z,
    float4* __restrict__ h4, ushort4* __restrict__ hb4, int N)
{
  int idx = blockIdx.x * 256 + threadIdx.x;
  if (idx >= N * 32) return;
  int n = idx >> 5, c = idx & 31;
  float4 v = emb4[z[n] * 32 + c];
  h4[idx] = v;
  hb4[idx] = make_ushort4(f2bf(v.x), f2bf(v.y), f2bf(v.z), f2bf(v.w));
}

// ---------------- fused GEMM chain (BM=32, single 32KB weight buffer) -----
__global__ __launch_bounds__(256) void k_fused(
    const unsigned short* __restrict__ X, long xstr,
    const unsigned short* __restrict__ Wa, long wastr,
    const float* __restrict__ ba, long bastr,
    const unsigned short* __restrict__ Wb, long wbstr,
    const float* __restrict__ bb, long bbstr,
    const float* __restrict__ R,
    void* __restrict__ out1, long o1str, int o1_bf16, int actB, int mulC,
    float dscale,
    const unsigned short* __restrict__ Wc, const float* __restrict__ bc,
    unsigned short* __restrict__ out2,
    const float* __restrict__ hw2, const float* __restrict__ hb2,
    const int* __restrict__ batchp, float* __restrict__ outp,
    int M)
{
  __shared__ unsigned short Xs[32][128];
  __shared__ unsigned short Wbuf[128][128];

  const int l = blockIdx.y;
  const int m0 = blockIdx.x * 32;
  const int tid = threadIdx.x;
  const unsigned short* Xb = X + (long)l * xstr;

  for (int idx = tid; idx < 512; idx += 256) {
    int r = idx >> 4, c = idx & 15;
    int m = m0 + r;
    int4 v = make_int4(0, 0, 0, 0);
    if (m < M) v = *(const int4*)(Xb + (long)m * 128 + c * 8);
    *(int4*)&Xs[r][(c ^ (r & 7)) << 3] = v;
  }
  {
    const unsigned short* W0 = Wa ? (Wa + (long)l * wastr) : (Wb + (long)l * wbstr);
    const int4* s = (const int4*)W0;
    int4* d = (int4*)Wbuf;
    for (int i = tid; i < 2048; i += 256) d[i] = s[i];
  }
  __syncthreads();

  const int wv = tid >> 6, lane = tid & 63;
  const int wr = wv >> 1, wc = wv & 1;
  const int lr = lane & 15, lk = lane >> 4;
  const int arow = (wr << 4) | lr;

  f32x4 acc[4];
  auto zacc = [&]() {
#pragma unroll
    for (int i = 0; i < 4; ++i)
#pragma unroll
      for (int j = 0; j < 4; ++j) acc[i][j] = 0.f;
  };
  auto gemm = [&]() {
#pragma unroll
    for (int kc = 0; kc < 4; ++kc) {
      int q = (kc << 2) | lk;
      bf16x8 a = *(const bf16x8*)&Xs[arow][(q ^ (arow & 7)) << 3];
#pragma unroll
      for (int nt = 0; nt < 4; ++nt) {
        int n = (wc << 6) | (nt << 4) | lr;
        bf16x8 b = *(const bf16x8*)(&Wbuf[0][0] + n * 128 + ((q ^ (n & 7)) << 3));
        acc[nt] = __builtin_amdgcn_mfma_f32_16x16x32_bf16(a, b, acc[nt], 0, 0, 0);
      }
    }
  };

  if (Wa) {
    const float* bab = ba + (long)l * bastr;
    zacc();
    gemm();
    __syncthreads();
#pragma unroll
    for (int nt = 0; nt < 4; ++nt) {
      int col = (wc << 6) | (nt << 4) | lr;
      float bv = bab[col];
#pragma unroll
      for (int r2 = 0; r2 < 4; ++r2) {
        int row = (wr << 4) | (lk << 2) | r2;
        float v2 = ssp_f(acc[nt][r2] + bv);
        int cch = col >> 3;
        Xs[row][((cch ^ (row & 7)) << 3) | (col & 7)] = f2bf(v2);
      }
    }
    {
      const int4* s = (const int4*)(Wb + (long)l * wbstr);
      int4* d = (int4*)Wbuf;
      for (int i = tid; i < 2048; i += 256) d[i] = s[i];
    }
    __syncthreads();
  }

  const float* bbb = bb + (long)l * bbstr;
  zacc();
  gemm();
  __syncthreads();

#pragma unroll
  for (int nt = 0; nt < 4; ++nt) {
    int col = (wc << 6) | (nt << 4) | lr;
    float bv = bbb[col];
#pragma unroll
    for (int r2 = 0; r2 < 4; ++r2) {
      int row = (wr << 4) | (lk << 2) | r2;
      int m = m0 + row;
      float v2 = acc[nt][r2] + bv;
      if (actB) v2 = ssp_f(v2);
      if (R && m < M) v2 += R[(long)m * 128 + col];
      if (mulC) {
        float d = (float)m * dscale;
        v2 *= 0.5f * (__cosf(d * (PI_F / 10.0f)) + 1.0f);
      }
      if (m < M && out1) {
        if (o1_bf16)
          ((unsigned short*)out1)[(long)l * o1str + (long)m * 128 + col] = f2bf(v2);
        else
          ((float*)out1)[(long)l * o1str + (long)m * 128 + col] = v2;
      }
      if (Wc) {
        int cch = col >> 3;
        Xs[row][((cch ^ (row & 7)) << 3) | (col & 7)] = f2bf(v2);
      }
    }
  }

  if (Wc) {
    {
      const int4* s = (const int4*)Wc;
      int4* d = (int4*)Wbuf;
      for (int i = tid; i < 2048; i += 256) d[i] = s[i];
    }
    __syncthreads();
    zacc();
    gemm();
    if (hw2) {
      if (wc == 0) {
        float b1v[4], w2v[4];
#pragma unroll
        for (int nt = 0; nt < 4; ++nt) {
          int col = (nt << 4) | lr;
          b1v[nt] = bc[col];
          w2v[nt] = hw2[col];
        }
        float bias2 = hb2[0];
#pragma unroll
        for (int r2 = 0; r2 < 4; ++r2) {
          float sv = 0.f;
#pragma unroll
          for (int nt = 0; nt < 4; ++nt)
            sv += ssp_f(acc[nt][r2] + b1v[nt]) * w2v[nt];
          sv += __shfl_xor(sv, 1);
          sv += __shfl_xor(sv, 2);
          sv += __shfl_xor(sv, 4);
          sv += __shfl_xor(sv, 8);
          if (lr == 0) {
            int m = m0 + (wr << 4) + (lk << 2) + r2;
            if (m < M) atomicAdd(&outp[batchp[m]], sv + bias2);
          }
        }
      }
    } else {
#pragma unroll
      for (int nt = 0; nt < 4; ++nt) {
        int col = (wc << 6) | (nt << 4) | lr;
        float bv = bc[col];
#pragma unroll
        for (int r2 = 0; r2 < 4; ++r2) {
          int row = (wr << 4) | (lk << 2) | r2;
          int m = m0 + row;
          if (m < M)
            out2[(long)m * 128 + col] = f2bf(acc[nt][r2] + bv);
        }
      }
    }
  }
}

// ---------------- conv: per-node gather, scalar csr, 8-wide pipelined -----
// Edges are bucket-sorted by source-row range (1MB hw slices) so the live
// gather working set (~1MB hw + 2MB T) fits each XCD's 4MB L2.
__global__ __launch_bounds__(256) void k_conv(
    const int* __restrict__ csr, const int* __restrict__ ptr,
    const unsigned short* __restrict__ T, const unsigned short* __restrict__ hw,
    unsigned short* __restrict__ convb, int N)
{
  int wid = __builtin_amdgcn_readfirstlane((blockIdx.x * 256 + threadIdx.x) >> 6);
  int lane = threadIdx.x & 63;
  if (wid >= N) return;
  int s = __builtin_amdgcn_readfirstlane(ptr[wid * NB]);
  int e = __builtin_amdgcn_readfirstlane(ptr[wid * NB + NB]);
  const int la = lane << 1;
  float ax[8], ay[8];
#pragma unroll
  for (int i = 0; i < 8; ++i) { ax[i] = 0.f; ay[i] = 0.f; }
  int j = s;
  if (j + 8 <= e) {
    int cc[8];
#pragma unroll
    for (int i = 0; i < 8; ++i) cc[i] = __builtin_amdgcn_readfirstlane(csr[j + i]);
    for (; j + 16 <= e; j += 8) {
      unsigned tv[8], hv[8];
#pragma unroll
      for (int i = 0; i < 8; ++i) {
        unsigned pr = (unsigned)cc[i];
        tv[i] = *(const unsigned*)(T + ((size_t)(pr & 8191u) << 7) + la);
        hv[i] = *(const unsigned*)(hw + ((size_t)(pr >> 13) << 7) + la);
      }
#pragma unroll
      for (int i = 0; i < 8; ++i) cc[i] = __builtin_amdgcn_readfirstlane(csr[j + 8 + i]);
#pragma unroll
      for (int i = 0; i < 8; ++i) {
        float w0 = __uint_as_float(tv[i] << 16), w1 = __uint_as_float(tv[i] & 0xffff0000u);
        float h0 = __uint_as_float(hv[i] << 16), h1 = __uint_as_float(hv[i] & 0xffff0000u);
        ax[i] = fmaf(w0, h0, ax[i]); ay[i] = fmaf(w1, h1, ay[i]);
      }
    }
    {
      unsigned tv[8], hv[8];
#pragma unroll
      for (int i = 0; i < 8; ++i) {
        unsigned pr = (unsigned)cc[i];
        tv[i] = *(const unsigned*)(T + ((size_t)(pr & 8191u) << 7) + la);
        hv[i] = *(const unsigned*)(hw + ((size_t)(pr >> 13) << 7) + la);
      }
#pragma unroll
      for (int i = 0; i < 8; ++i) {
        float w0 = __uint_as_float(tv[i] << 16), w1 = __uint_as_float(tv[i] & 0xffff0000u);
        float h0 = __uint_as_float(hv[i] << 16), h1 = __uint_as_float(hv[i] & 0xffff0000u);
        ax[i] = fmaf(w0, h0, ax[i]); ay[i] = fmaf(w1, h1, ay[i]);
      }
    }
    j += 8;
  }
  for (; j < e; ++j) {
    unsigned pr = (unsigned)__builtin_amdgcn_readfirstlane(csr[j]);
    unsigned tv = *(const unsigned*)(T + ((size_t)(pr & 8191u) << 7) + la);
    unsigned hv = *(const unsigned*)(hw + ((size_t)(pr >> 13) << 7) + la);
    float w0 = __uint_as_float(tv << 16), w1 = __uint_as_float(tv & 0xffff0000u);
    float h0 = __uint_as_float(hv << 16), h1 = __uint_as_float(hv & 0xffff0000u);
    ax[0] = fmaf(w0, h0, ax[0]); ay[0] = fmaf(w1, h1, ay[0]);
  }
  float axs = ((ax[0] + ax[1]) + (ax[2] + ax[3])) + ((ax[4] + ax[5]) + (ax[6] + ax[7]));
  float ays = ((ay[0] + ay[1]) + (ay[2] + ay[3])) + ((ay[4] + ay[5]) + (ay[6] + ay[7]));
  unsigned outw = (unsigned)f2bf(axs) | ((unsigned)f2bf(ays) << 16);
  *(unsigned*)(convb + ((size_t)wid << 7) + la) = outw;
}

extern "C" void kernel_launch(void* const* d_in, const int* in_sizes, int n_in,
                              void* d_out, int out_size, void* d_ws, size_t ws_size,
                              hipStream_t stream) {
  (void)n_in; (void)ws_size;
  const float* pos     = (const float*)d_in[0];
  const int*   z       = (const int*)d_in[1];
  const int*   batch   = (const int*)d_in[2];
  const int*   ei      = (const int*)d_in[3];
  const float* emb     = (const float*)d_in[4];
  const float* mlp_w1  = (const float*)d_in[5];
  const float* mlp_b1  = (const float*)d_in[6];
  const float* mlp_w2  = (const float*)d_in[7];
  const float* mlp_b2  = (const float*)d_in[8];
  const float* aw_w    = (const float*)d_in[9];
  const float* aw_b    = (const float*)d_in[10];
  const float* out_w1  = (const float*)d_in[11];
  const float* out_b1  = (const float*)d_in[12];
  const float* out_w2  = (const float*)d_in[13];
  const float* out_b2  = (const float*)d_in[14];
  const float* head_w1 = (const float*)d_in[15];
  const float* head_b1 = (const float*)d_in[16];
  const float* head_w2 = (const float*)d_in[17];
  const float* head_b2 = (const float*)d_in[18];

  const int N  = in_sizes[0] / 3;
  const int E  = in_sizes[3] / 2;
  const int NG = out_size;
  const int L  = in_sizes[5] / (NG_GAUSS * HID);

  char* ws = (char*)d_ws;
  size_t off = 0;
  auto alloc = [&](size_t bytes) -> void* {
    off = (off + 255) & ~(size_t)255;
    void* p = ws + off;
    off += bytes;
    return p;
  };

  const size_t nh = (size_t)N * HID;
  float* h_buf = (float*)alloc(nh * 4 > (size_t)E * 4 ? nh * 4 : (size_t)E * 4);
  int*   epack = (int*)h_buf;                   // alias (disjoint lifetime)
  unsigned short* hb    = (unsigned short*)alloc(nh * 2);
  unsigned short* hw    = (unsigned short*)alloc(nh * 2);
  unsigned short* convb = (unsigned short*)alloc(
      nh * 2 > (size_t)TBL_P * 128 * 2 ? nh * 2 : (size_t)TBL_P * 128 * 2);
  unsigned short* EA    = convb;                // alias (EA used pre-conv)
  int* csr = (int*)alloc((size_t)E * 4);
  unsigned short* T   = (unsigned short*)alloc((size_t)L * TBL_P * 128 * 2);
  unsigned short* awt = (unsigned short*)alloc((size_t)L * 16384 * 2);
  unsigned short* o1t = (unsigned short*)alloc((size_t)L * 16384 * 2);
  unsigned short* o2t = (unsigned short*)alloc((size_t)L * 16384 * 2);
  unsigned short* m2t = (unsigned short*)alloc((size_t)L * 16384 * 2);
  unsigned short* m1t = (unsigned short*)alloc((size_t)L * 16384 * 2);
  unsigned short* hwt = (unsigned short*)alloc((size_t)16384 * 2);
  int* deg    = (int*)alloc((size_t)N * NB * 4);
  int* ptr    = (int*)alloc(((size_t)N * NB + 1) * 4);
  int* cursor = (int*)alloc((size_t)N * NB * 4);
  int* bsum   = (int*)alloc((size_t)1024 * 4);

  const int M = N * NB;
  const int G = (M + 2047) / 2048;

  hipMemsetAsync(deg, 0, (size_t)M * 4, stream);
  hipMemsetAsync(cursor, 0, (size_t)M * 4, stream);
  hipMemsetAsync(d_out, 0, (size_t)NG * 4, stream);

  int egrid = (E + 255) / 256;
  k_edge_pre<<<egrid, 256, 0, stream>>>(pos, ei, E, epack, deg);
  k_scan1<<<G, 1024, 0, stream>>>(deg, ptr, bsum, M);
  k_scan2<<<1, 1024, 0, stream>>>(bsum, G);
  k_scan3<<<G, 1024, 0, stream>>>(ptr, bsum, M, G);
  k_csr_scatter<<<egrid, 256, 0, stream>>>(ei + E, epack, ptr, cursor, csr, E);

  k_wprep<<<dim3(L, 6, 2), 256, 0, stream>>>(aw_w, out_w1, out_w2, mlp_w2,
                                             mlp_w1, head_w1,
                                             awt, o1t, o2t, m2t, m1t, hwt);
  k_ea_build<<<TBL_P, 128, 0, stream>>>(EA);

  // filter tables: T_l = ssp(ssp(EA@w1+b1)@w2+b2) * C(d), bf16, batched
  k_fused<<<dim3(TBL_P / 32, L), 256, 0, stream>>>(
      EA, 0L,
      m1t, 16384L, mlp_b1, 128L,
      m2t, 16384L, mlp_b2, 128L,
      (const float*)0,
      T, (long)TBL_P * 128, 1 /*bf16*/, 1 /*ssp*/, 1 /*mulC*/, TBL_DT,
      (const unsigned short*)0, (const float*)0, (unsigned short*)0,
      (const float*)0, (const float*)0, (const int*)0, (float*)0,
      TBL_P);

  k_h_init<<<(N * 32 + 255) / 256, 256, 0, stream>>>(
      (const float4*)emb, z, (float4*)h_buf, (ushort4*)hb, N);

  const int ngrid = (N + 31) / 32;
  const int wgrid = (N * 64 + 255) / 256;

  // initial hw = h0 @ aw_w[0] + aw_b[0]
  k_fused<<<dim3(ngrid, 1), 256, 0, stream>>>(
      hb, 0L,
      (const unsigned short*)0, 0L, (const float*)0, 0L,
      awt, 0L, aw_b, 0L,
      (const float*)0,
      hw, 0L, 1 /*bf16*/, 0, 0, 0.f,
      (const unsigned short*)0, (const float*)0, (unsigned short*)0,
      (const float*)0, (const float*)0, (const int*)0, (float*)0,
      N);

  for (int l = 0; l < L; ++l) {
    k_conv<<<wgrid, 256, 0, stream>>>(
        csr, ptr, T + (size_t)l * TBL_P * 128, hw, convb, N);
    const int last = (l + 1 == L);
    const unsigned short* Wc = last ? hwt : (awt + (size_t)(l + 1) * 16384);
    const float* bc = last ? head_b1 : (aw_b + (size_t)(l + 1) * 128);
    k_fused<<<dim3(ngrid, 1), 256, 0, stream>>>(
        convb, 0L,
        o1t + (size_t)l * 16384, 0L, out_b1 + (size_t)l * 128, 0L,
        o2t + (size_t)l * 16384, 0L, out_b2 + (size_t)l * 128, 0L,
        h_buf,
        last ? (void*)0 : (void*)h_buf, 0L, 0 /*fp32*/, 0 /*no act*/, 0, 0.f,
        Wc, bc, last ? (unsigned short*)0 : hw,
        last ? head_w2 : (const float*)0, last ? head_b2 : (const float*)0,
        last ? batch : (const int*)0, last ? (float*)d_out : (float*)0,
        N);
  }
}

// Round 11
// 360.700 us; speedup vs baseline: 1.7555x; 1.0800x over previous
//
#include <hip/hip_runtime.h>
#include <math.h>

#define HID 128
#define NG_GAUSS 50
#define TBL_P 4096
#define TBL_DMAX 12.8f
#define TBL_DT (TBL_DMAX / (float)TBL_P)
#define TBL_INV_DT ((float)TBL_P / TBL_DMAX)
#define PI_F 3.14159265358979323846f
#define NB 16          // source-row buckets (2048 rows = 0.5MB hw each)
#define BSH 11         // bucket shift

typedef short bf16x8 __attribute__((ext_vector_type(8)));
typedef float f32x4 __attribute__((ext_vector_type(4)));

// fast shifted-softplus via HW transcendentals (v_exp_f32 / v_log_f32)
__device__ __forceinline__ float ssp_f(float x) {
  float e = __expf(-fabsf(x));
  return fmaxf(x, 0.f) + __logf(1.f + e) - 0.69314718055994530942f;
}
__device__ __forceinline__ unsigned short f2bf(float x) {
  unsigned u = __float_as_uint(x);
  unsigned r = (u + 0x7FFFu + ((u >> 16) & 1u)) >> 16;
  return (unsigned short)r;
}
__device__ __forceinline__ float bf2f_s(unsigned short v) {
  return __uint_as_float((unsigned)v << 16);
}

// ---------------- edge precompute: pack (row<<13|i0), cull, bucket deg ----
__global__ __launch_bounds__(256) void k_edge_pre(
    const float* __restrict__ pos, const int* __restrict__ ei,
    int E, int* __restrict__ epack, int* __restrict__ deg)
{
  int e = blockIdx.x * 256 + threadIdx.x;
  if (e >= E) return;
  int r = ei[e];
  int c = ei[E + e];
  float dx = pos[3*r+0] - pos[3*c+0];
  float dy = pos[3*r+1] - pos[3*c+1];
  float dz = pos[3*r+2] - pos[3*c+2];
  float d = sqrtf(dx*dx + dy*dy + dz*dz);
  int i0 = (int)(d * TBL_INV_DT + 0.5f);
  if (i0 >= TBL_P) { epack[e] = -1; return; }  // d>=12.8: gaussians underflow,
                                               // zero biases => filter exactly 0
  epack[e] = (r << 13) | i0;
  atomicAdd(&deg[c * NB + (r >> BSH)], 1);
}

// ---------------- multi-block exclusive scan (3 phases) -------------------
__global__ __launch_bounds__(1024) void k_scan1(
    const int* __restrict__ deg, int* __restrict__ ptr,
    int* __restrict__ bsum, int M)
{
  __shared__ int wsum[16];
  int base = blockIdx.x * 2048;
  int t = threadIdx.x;
  int i0 = base + 2 * t;
  int v0 = (i0 < M) ? deg[i0] : 0;
  int v1 = (i0 + 1 < M) ? deg[i0 + 1] : 0;
  int s = v0 + v1;
  int lane = t & 63, w = t >> 6;
  int ps = s;
  for (int o = 1; o < 64; o <<= 1) { int x = __shfl_up(ps, o); if (lane >= o) ps += x; }
  if (lane == 63) wsum[w] = ps;
  __syncthreads();
  if (w == 0 && lane < 16) {
    int v = wsum[lane];
    int pv = v;
    for (int o = 1; o < 16; o <<= 1) { int x = __shfl_up(pv, o); if (lane >= o) pv += x; }
    wsum[lane] = pv - v;  // exclusive
  }
  __syncthreads();
  int ex = wsum[w] + ps - s;
  if (i0 < M) ptr[i0] = ex;
  if (i0 + 1 < M) ptr[i0 + 1] = ex + v0;
  if (t == 1023) bsum[blockIdx.x] = ex + s;
}

__global__ __launch_bounds__(1024) void k_scan2(int* __restrict__ bsum, int G)
{
  __shared__ int wsum[16];
  int t = threadIdx.x;
  int s = (t < G) ? bsum[t] : 0;
  int lane = t & 63, w = t >> 6;
  int ps = s;
  for (int o = 1; o < 64; o <<= 1) { int x = __shfl_up(ps, o); if (lane >= o) ps += x; }
  if (lane == 63) wsum[w] = ps;
  __syncthreads();
  if (w == 0 && lane < 16) {
    int v = wsum[lane];
    int pv = v;
    for (int o = 1; o < 16; o <<= 1) { int x = __shfl_up(pv, o); if (lane >= o) pv += x; }
    wsum[lane] = pv - v;
  }
  __syncthreads();
  int ex = wsum[w] + ps - s;
  if (t < G) bsum[t] = ex;
  if (t == G - 1) bsum[G] = ex + s;
}

__global__ __launch_bounds__(1024) void k_scan3(
    int* __restrict__ ptr, const int* __restrict__ bsum, int M, int G)
{
  int base = blockIdx.x * 2048;
  int t = threadIdx.x;
  int add = bsum[blockIdx.x];
  int i0 = base + 2 * t;
  if (i0 < M) ptr[i0] += add;
  if (i0 + 1 < M) ptr[i0 + 1] += add;
  if (blockIdx.x == 0 && t == 0) ptr[M] = bsum[G];
}

// ---------------- scatter edges into bucket-sorted CSR order --------------
__global__ __launch_bounds__(256) void k_csr_scatter(
    const int* __restrict__ col, const int* __restrict__ epack,
    const int* __restrict__ ptr, int* __restrict__ cursor,
    int* __restrict__ csr, int E)
{
  int e = blockIdx.x * 256 + threadIdx.x;
  if (e >= E) return;
  int p = epack[e];
  if (p < 0) return;
  int c = col[e];
  int idx = c * NB + ((p >> 13) >> BSH);
  int slot = ptr[idx] + atomicAdd(&cursor[idx], 1);
  csr[slot] = p;
}

// ---------------- weight prep: bf16, transposed [n][k], chunk-XOR swizzle -
__global__ __launch_bounds__(256) void k_wprep(
    const float* __restrict__ aw_w, const float* __restrict__ out_w1,
    const float* __restrict__ out_w2, const float* __restrict__ mlp_w2,
    const float* __restrict__ mlp_w1, const float* __restrict__ head_w1,
    unsigned short* __restrict__ awt, unsigned short* __restrict__ o1t,
    unsigned short* __restrict__ o2t, unsigned short* __restrict__ m2t,
    unsigned short* __restrict__ m1t, unsigned short* __restrict__ hwt)
{
  __shared__ float Wl[64][132];
  int l = blockIdx.x, t = blockIdx.y;
  int k0 = blockIdx.z * 64;
  const float* src; unsigned short* dst; int K; int NCOL = 128;
  switch (t) {
    case 0:  src = aw_w;   dst = awt; K = 128; break;
    case 1:  src = out_w1; dst = o1t; K = 128; break;
    case 2:  src = out_w2; dst = o2t; K = 128; break;
    case 3:  src = mlp_w2; dst = m2t; K = 128; break;
    case 4:  src = mlp_w1; dst = m1t; K = NG_GAUSS; break;
    default:
      if (l) return;
      src = head_w1; dst = hwt; K = 128; NCOL = 64; break;
  }
  src += (long)l * K * NCOL;
  dst += (long)l * 128 * 128;
  const int tid = threadIdx.x;
  for (int idx = tid; idx < 64 * 128; idx += 256) {
    int kk = idx >> 7, n = idx & 127;
    int k = k0 + kk;
    Wl[kk][n] = (k < K && n < NCOL) ? src[(long)k * NCOL + n] : 0.f;
  }
  __syncthreads();
  for (int idx = tid; idx < 128 * 8; idx += 256) {
    int n = idx >> 3, pl = idx & 7;
    int p = (k0 >> 3) + pl;
    int q = p ^ (n & 7);
    int kk = (q << 3) - k0;
    ushort4 lo = make_ushort4(f2bf(Wl[kk+0][n]), f2bf(Wl[kk+1][n]),
                              f2bf(Wl[kk+2][n]), f2bf(Wl[kk+3][n]));
    ushort4 hi = make_ushort4(f2bf(Wl[kk+4][n]), f2bf(Wl[kk+5][n]),
                              f2bf(Wl[kk+6][n]), f2bf(Wl[kk+7][n]));
    *(ushort4*)(dst + ((long)n << 7) + (p << 3)) = lo;
    *(ushort4*)(dst + ((long)n << 7) + (p << 3) + 4) = hi;
  }
}

// ---------------- gaussian feature table bf16 [TBL_P][128] zero-padded ----
__global__ void k_ea_build(unsigned short* __restrict__ EA)
{
  int p = blockIdx.x;
  int g = threadIdx.x; // 128 threads
  float v = 0.f;
  if (g < NG_GAUSS) {
    float step = 10.0f / 49.0f;
    float off = g * step;
    float coeff = -0.5f / (step * step);
    float t = p * TBL_DT - off;
    v = __expf(coeff * t * t);
  }
  EA[p * 128 + g] = f2bf(v);
}

// ---------------- h init: h = emb[z] (bf16) -------------------------------
__global__ __launch_bounds__(256) void k_h_init(
    const float* __restrict__ emb, const int* __restrict__ z,
    unsigned short* __restrict__ h, int N)
{
  int idx = blockIdx.x * 256 + threadIdx.x;
  if (idx >= N * 16) return;
  int n = idx >> 4, c = idx & 15;
  const float* er = emb + (long)z[n] * 128 + (c << 3);
  float4 lo = *(const float4*)er;
  float4 hi = *(const float4*)(er + 4);
  alignas(16) unsigned short u[8];
  u[0]=f2bf(lo.x); u[1]=f2bf(lo.y); u[2]=f2bf(lo.z); u[3]=f2bf(lo.w);
  u[4]=f2bf(hi.x); u[5]=f2bf(hi.y); u[6]=f2bf(hi.z); u[7]=f2bf(hi.w);
  *(int4*)(h + (long)n * 128 + (c << 3)) = *(int4*)u;
}

// ---------------- fused GEMM chain (BM=32, single 32KB weight buffer) -----
// Stage A (if Wa): tmp = ssp(X@Wa + ba)
// Stage B: v = tmp@Wb + bb; [ssp]; [+R bf16 (residual), write back]; [*C]
// Stage C (if Wc): out2 = v@Wc + bc  OR fused head -> atomicAdd(outp)
__global__ __launch_bounds__(256) void k_fused(
    const unsigned short* __restrict__ X, long xstr,
    const unsigned short* __restrict__ Wa, long wastr,
    const float* __restrict__ ba, long bastr,
    const unsigned short* __restrict__ Wb, long wbstr,
    const float* __restrict__ bb, long bbstr,
    unsigned short* __restrict__ R,       // bf16 residual (read+write unless ronly)
    int r_write,
    void* __restrict__ out1, long o1str, int o1_bf16, int actB, int mulC,
    float dscale,
    const unsigned short* __restrict__ Wc, const float* __restrict__ bc,
    unsigned short* __restrict__ out2,
    const float* __restrict__ hw2, const float* __restrict__ hb2,
    const int* __restrict__ batchp, float* __restrict__ outp,
    int M)
{
  __shared__ unsigned short Xs[32][128];
  __shared__ unsigned short Wbuf[128][128];

  const int l = blockIdx.y;
  const int m0 = blockIdx.x * 32;
  const int tid = threadIdx.x;
  const unsigned short* Xb = X + (long)l * xstr;

  for (int idx = tid; idx < 512; idx += 256) {
    int r = idx >> 4, c = idx & 15;
    int m = m0 + r;
    int4 v = make_int4(0, 0, 0, 0);
    if (m < M) v = *(const int4*)(Xb + (long)m * 128 + c * 8);
    *(int4*)&Xs[r][(c ^ (r & 7)) << 3] = v;
  }
  {
    const unsigned short* W0 = Wa ? (Wa + (long)l * wastr) : (Wb + (long)l * wbstr);
    const int4* s = (const int4*)W0;
    int4* d = (int4*)Wbuf;
    for (int i = tid; i < 2048; i += 256) d[i] = s[i];
  }
  __syncthreads();

  const int wv = tid >> 6, lane = tid & 63;
  const int wr = wv >> 1, wc = wv & 1;
  const int lr = lane & 15, lk = lane >> 4;
  const int arow = (wr << 4) | lr;

  f32x4 acc[4];
  auto zacc = [&]() {
#pragma unroll
    for (int i = 0; i < 4; ++i)
#pragma unroll
      for (int j = 0; j < 4; ++j) acc[i][j] = 0.f;
  };
  auto gemm = [&]() {
#pragma unroll
    for (int kc = 0; kc < 4; ++kc) {
      int q = (kc << 2) | lk;
      bf16x8 a = *(const bf16x8*)&Xs[arow][(q ^ (arow & 7)) << 3];
#pragma unroll
      for (int nt = 0; nt < 4; ++nt) {
        int n = (wc << 6) | (nt << 4) | lr;
        bf16x8 b = *(const bf16x8*)(&Wbuf[0][0] + n * 128 + ((q ^ (n & 7)) << 3));
        acc[nt] = __builtin_amdgcn_mfma_f32_16x16x32_bf16(a, b, acc[nt], 0, 0, 0);
      }
    }
  };

  if (Wa) {
    const float* bab = ba + (long)l * bastr;
    zacc();
    gemm();
    __syncthreads();
#pragma unroll
    for (int nt = 0; nt < 4; ++nt) {
      int col = (wc << 6) | (nt << 4) | lr;
      float bv = bab[col];
#pragma unroll
      for (int r2 = 0; r2 < 4; ++r2) {
        int row = (wr << 4) | (lk << 2) | r2;
        float v2 = ssp_f(acc[nt][r2] + bv);
        int cch = col >> 3;
        Xs[row][((cch ^ (row & 7)) << 3) | (col & 7)] = f2bf(v2);
      }
    }
    {
      const int4* s = (const int4*)(Wb + (long)l * wbstr);
      int4* d = (int4*)Wbuf;
      for (int i = tid; i < 2048; i += 256) d[i] = s[i];
    }
    __syncthreads();
  }

  const float* bbb = bb + (long)l * bbstr;
  zacc();
  gemm();
  __syncthreads();

#pragma unroll
  for (int nt = 0; nt < 4; ++nt) {
    int col = (wc << 6) | (nt << 4) | lr;
    float bv = bbb[col];
#pragma unroll
    for (int r2 = 0; r2 < 4; ++r2) {
      int row = (wr << 4) | (lk << 2) | r2;
      int m = m0 + row;
      float v2 = acc[nt][r2] + bv;
      if (actB) v2 = ssp_f(v2);
      if (R && m < M) {
        v2 += bf2f_s(R[(long)m * 128 + col]);
        if (r_write) R[(long)m * 128 + col] = f2bf(v2);
      }
      if (mulC) {
        float d = (float)m * dscale;
        v2 *= 0.5f * (__cosf(d * (PI_F / 10.0f)) + 1.0f);
      }
      if (m < M && out1) {
        if (o1_bf16)
          ((unsigned short*)out1)[(long)l * o1str + (long)m * 128 + col] = f2bf(v2);
        else
          ((float*)out1)[(long)l * o1str + (long)m * 128 + col] = v2;
      }
      if (Wc) {
        int cch = col >> 3;
        Xs[row][((cch ^ (row & 7)) << 3) | (col & 7)] = f2bf(v2);
      }
    }
  }

  if (Wc) {
    {
      const int4* s = (const int4*)Wc;
      int4* d = (int4*)Wbuf;
      for (int i = tid; i < 2048; i += 256) d[i] = s[i];
    }
    __syncthreads();
    zacc();
    gemm();
    if (hw2) {
      if (wc == 0) {
        float b1v[4], w2v[4];
#pragma unroll
        for (int nt = 0; nt < 4; ++nt) {
          int col = (nt << 4) | lr;
          b1v[nt] = bc[col];
          w2v[nt] = hw2[col];
        }
        float bias2 = hb2[0];
#pragma unroll
        for (int r2 = 0; r2 < 4; ++r2) {
          float sv = 0.f;
#pragma unroll
          for (int nt = 0; nt < 4; ++nt)
            sv += ssp_f(acc[nt][r2] + b1v[nt]) * w2v[nt];
          sv += __shfl_xor(sv, 1);
          sv += __shfl_xor(sv, 2);
          sv += __shfl_xor(sv, 4);
          sv += __shfl_xor(sv, 8);
          if (lr == 0) {
            int m = m0 + (wr << 4) + (lk << 2) + r2;
            if (m < M) atomicAdd(&outp[batchp[m]], sv + bias2);
          }
        }
      }
    } else {
#pragma unroll
      for (int nt = 0; nt < 4; ++nt) {
        int col = (wc << 6) | (nt << 4) | lr;
        float bv = bc[col];
#pragma unroll
        for (int r2 = 0; r2 < 4; ++r2) {
          int row = (wr << 4) | (lk << 2) | r2;
          int m = m0 + row;
          if (m < M)
            out2[(long)m * 128 + col] = f2bf(acc[nt][r2] + bv);
        }
      }
    }
  }
}

// ---------------- conv: per-node gather, scalar csr, 8-wide pipelined -----
// Edges bucket-sorted by source-row range (0.5MB hw slices); T (1MB) + slice
// stay L2-resident per XCD.
__global__ __launch_bounds__(256) void k_conv(
    const int* __restrict__ csr, const int* __restrict__ ptr,
    const unsigned short* __restrict__ T, const unsigned short* __restrict__ hw,
    unsigned short* __restrict__ convb, int N)
{
  int wid = __builtin_amdgcn_readfirstlane((blockIdx.x * 256 + threadIdx.x) >> 6);
  int lane = threadIdx.x & 63;
  if (wid >= N) return;
  int s = __builtin_amdgcn_readfirstlane(ptr[wid * NB]);
  int e = __builtin_amdgcn_readfirstlane(ptr[wid * NB + NB]);
  const int la = lane << 1;
  float ax[8], ay[8];
#pragma unroll
  for (int i = 0; i < 8; ++i) { ax[i] = 0.f; ay[i] = 0.f; }
  int j = s;
  if (j + 8 <= e) {
    int cc[8];
#pragma unroll
    for (int i = 0; i < 8; ++i) cc[i] = __builtin_amdgcn_readfirstlane(csr[j + i]);
    for (; j + 16 <= e; j += 8) {
      unsigned tv[8], hv[8];
#pragma unroll
      for (int i = 0; i < 8; ++i) {
        unsigned pr = (unsigned)cc[i];
        tv[i] = *(const unsigned*)(T + ((size_t)(pr & 4095u) << 7) + la);
        hv[i] = *(const unsigned*)(hw + ((size_t)(pr >> 13) << 7) + la);
      }
#pragma unroll
      for (int i = 0; i < 8; ++i) cc[i] = __builtin_amdgcn_readfirstlane(csr[j + 8 + i]);
#pragma unroll
      for (int i = 0; i < 8; ++i) {
        float w0 = __uint_as_float(tv[i] << 16), w1 = __uint_as_float(tv[i] & 0xffff0000u);
        float h0 = __uint_as_float(hv[i] << 16), h1 = __uint_as_float(hv[i] & 0xffff0000u);
        ax[i] = fmaf(w0, h0, ax[i]); ay[i] = fmaf(w1, h1, ay[i]);
      }
    }
    {
      unsigned tv[8], hv[8];
#pragma unroll
      for (int i = 0; i < 8; ++i) {
        unsigned pr = (unsigned)cc[i];
        tv[i] = *(const unsigned*)(T + ((size_t)(pr & 4095u) << 7) + la);
        hv[i] = *(const unsigned*)(hw + ((size_t)(pr >> 13) << 7) + la);
      }
#pragma unroll
      for (int i = 0; i < 8; ++i) {
        float w0 = __uint_as_float(tv[i] << 16), w1 = __uint_as_float(tv[i] & 0xffff0000u);
        float h0 = __uint_as_float(hv[i] << 16), h1 = __uint_as_float(hv[i] & 0xffff0000u);
        ax[i] = fmaf(w0, h0, ax[i]); ay[i] = fmaf(w1, h1, ay[i]);
      }
    }
    j += 8;
  }
  for (; j < e; ++j) {
    unsigned pr = (unsigned)__builtin_amdgcn_readfirstlane(csr[j]);
    unsigned tv = *(const unsigned*)(T + ((size_t)(pr & 4095u) << 7) + la);
    unsigned hv = *(const unsigned*)(hw + ((size_t)(pr >> 13) << 7) + la);
    float w0 = __uint_as_float(tv << 16), w1 = __uint_as_float(tv & 0xffff0000u);
    float h0 = __uint_as_float(hv << 16), h1 = __uint_as_float(hv & 0xffff0000u);
    ax[0] = fmaf(w0, h0, ax[0]); ay[0] = fmaf(w1, h1, ay[0]);
  }
  float axs = ((ax[0] + ax[1]) + (ax[2] + ax[3])) + ((ax[4] + ax[5]) + (ax[6] + ax[7]));
  float ays = ((ay[0] + ay[1]) + (ay[2] + ay[3])) + ((ay[4] + ay[5]) + (ay[6] + ay[7]));
  unsigned outw = (unsigned)f2bf(axs) | ((unsigned)f2bf(ays) << 16);
  *(unsigned*)(convb + ((size_t)wid << 7) + la) = outw;
}

extern "C" void kernel_launch(void* const* d_in, const int* in_sizes, int n_in,
                              void* d_out, int out_size, void* d_ws, size_t ws_size,
                              hipStream_t stream) {
  (void)n_in; (void)ws_size;
  const float* pos     = (const float*)d_in[0];
  const int*   z       = (const int*)d_in[1];
  const int*   batch   = (const int*)d_in[2];
  const int*   ei      = (const int*)d_in[3];
  const float* emb     = (const float*)d_in[4];
  const float* mlp_w1  = (const float*)d_in[5];
  const float* mlp_b1  = (const float*)d_in[6];
  const float* mlp_w2  = (const float*)d_in[7];
  const float* mlp_b2  = (const float*)d_in[8];
  const float* aw_w    = (const float*)d_in[9];
  const float* aw_b    = (const float*)d_in[10];
  const float* out_w1  = (const float*)d_in[11];
  const float* out_b1  = (const float*)d_in[12];
  const float* out_w2  = (const float*)d_in[13];
  const float* out_b2  = (const float*)d_in[14];
  const float* head_w1 = (const float*)d_in[15];
  const float* head_b1 = (const float*)d_in[16];
  const float* head_w2 = (const float*)d_in[17];
  const float* head_b2 = (const float*)d_in[18];

  const int N  = in_sizes[0] / 3;
  const int E  = in_sizes[3] / 2;
  const int NG = out_size;
  const int L  = in_sizes[5] / (NG_GAUSS * HID);

  char* ws = (char*)d_ws;
  size_t off = 0;
  auto alloc = [&](size_t bytes) -> void* {
    off = (off + 255) & ~(size_t)255;
    void* p = ws + off;
    off += bytes;
    return p;
  };

  const size_t nh2 = (size_t)N * HID * 2;   // bf16 [N][128]
  unsigned short* h = (unsigned short*)alloc(nh2 > (size_t)E * 4 ? nh2 : (size_t)E * 4);
  int* epack = (int*)h;                     // alias (disjoint lifetime)
  unsigned short* hw    = (unsigned short*)alloc(nh2);
  unsigned short* convb = (unsigned short*)alloc(
      nh2 > (size_t)TBL_P * 128 * 2 ? nh2 : (size_t)TBL_P * 128 * 2);
  unsigned short* EA    = convb;            // alias (EA used pre-conv)
  int* csr = (int*)alloc((size_t)E * 4);
  unsigned short* T   = (unsigned short*)alloc((size_t)L * TBL_P * 128 * 2);
  unsigned short* awt = (unsigned short*)alloc((size_t)L * 16384 * 2);
  unsigned short* o1t = (unsigned short*)alloc((size_t)L * 16384 * 2);
  unsigned short* o2t = (unsigned short*)alloc((size_t)L * 16384 * 2);
  unsigned short* m2t = (unsigned short*)alloc((size_t)L * 16384 * 2);
  unsigned short* m1t = (unsigned short*)alloc((size_t)L * 16384 * 2);
  unsigned short* hwt = (unsigned short*)alloc((size_t)16384 * 2);
  int* deg    = (int*)alloc((size_t)N * NB * 4);
  int* ptr    = (int*)alloc(((size_t)N * NB + 1) * 4);
  int* cursor = (int*)alloc((size_t)N * NB * 4);
  int* bsum   = (int*)alloc((size_t)4096 * 4);

  const int M = N * NB;
  const int G = (M + 2047) / 2048;

  hipMemsetAsync(deg, 0, (size_t)M * 4, stream);
  hipMemsetAsync(cursor, 0, (size_t)M * 4, stream);
  hipMemsetAsync(d_out, 0, (size_t)NG * 4, stream);

  int egrid = (E + 255) / 256;
  k_edge_pre<<<egrid, 256, 0, stream>>>(pos, ei, E, epack, deg);
  k_scan1<<<G, 1024, 0, stream>>>(deg, ptr, bsum, M);
  k_scan2<<<1, 1024, 0, stream>>>(bsum, G);
  k_scan3<<<G, 1024, 0, stream>>>(ptr, bsum, M, G);
  k_csr_scatter<<<egrid, 256, 0, stream>>>(ei + E, epack, ptr, cursor, csr, E);

  k_wprep<<<dim3(L, 6, 2), 256, 0, stream>>>(aw_w, out_w1, out_w2, mlp_w2,
                                             mlp_w1, head_w1,
                                             awt, o1t, o2t, m2t, m1t, hwt);
  k_ea_build<<<TBL_P, 128, 0, stream>>>(EA);

  // filter tables: T_l = ssp(ssp(EA@w1+b1)@w2+b2) * C(d), bf16, batched
  k_fused<<<dim3(TBL_P / 32, L), 256, 0, stream>>>(
      EA, 0L,
      m1t, 16384L, mlp_b1, 128L,
      m2t, 16384L, mlp_b2, 128L,
      (unsigned short*)0, 0,
      T, (long)TBL_P * 128, 1 /*bf16*/, 1 /*ssp*/, 1 /*mulC*/, TBL_DT,
      (const unsigned short*)0, (const float*)0, (unsigned short*)0,
      (const float*)0, (const float*)0, (const int*)0, (float*)0,
      TBL_P);

  k_h_init<<<(N * 16 + 255) / 256, 256, 0, stream>>>(emb, z, h, N);

  const int ngrid = (N + 31) / 32;
  const int wgrid = (N * 64 + 255) / 256;

  // initial hw = h0 @ aw_w[0] + aw_b[0]
  k_fused<<<dim3(ngrid, 1), 256, 0, stream>>>(
      h, 0L,
      (const unsigned short*)0, 0L, (const float*)0, 0L,
      awt, 0L, aw_b, 0L,
      (unsigned short*)0, 0,
      hw, 0L, 1 /*bf16*/, 0, 0, 0.f,
      (const unsigned short*)0, (const float*)0, (unsigned short*)0,
      (const float*)0, (const float*)0, (const int*)0, (float*)0,
      N);

  for (int l = 0; l < L; ++l) {
    k_conv<<<wgrid, 256, 0, stream>>>(
        csr, ptr, T + (size_t)l * TBL_P * 128, hw, convb, N);
    const int last = (l + 1 == L);
    const unsigned short* Wc = last ? hwt : (awt + (size_t)(l + 1) * 16384);
    const float* bc = last ? head_b1 : (aw_b + (size_t)(l + 1) * 128);
    k_fused<<<dim3(ngrid, 1), 256, 0, stream>>>(
        convb, 0L,
        o1t + (size_t)l * 16384, 0L, out_b1 + (size_t)l * 128, 0L,
        o2t + (size_t)l * 16384, 0L, out_b2 + (size_t)l * 128, 0L,
        h, last ? 0 : 1 /*write residual back unless final*/,
        (void*)0, 0L, 0, 0 /*no act*/, 0, 0.f,
        Wc, bc, last ? (unsigned short*)0 : hw,
        last ? head_w2 : (const float*)0, last ? head_b2 : (const float*)0,
        last ? batch : (const int*)0, last ? (float*)d_out : (float*)0,
        N);
  }
}